// Round 1
// baseline (359.239 us; speedup 1.0000x reference)
//
#include <hip/hip_runtime.h>
#include <hip/hip_bf16.h>
#include <cmath>

#define BN_EPS 1e-6f
typedef unsigned int u32;
typedef __attribute__((ext_vector_type(8))) short short8;   // 8 bf16 (4 VGPRs)
typedef __attribute__((ext_vector_type(4))) float f32x4;    // MFMA accum

constexpr int B_    = 4;
constexpr int N_    = 16384;
constexpr int K_    = 16;
constexpr int C_IMG = 54;
constexpr int C1    = 64;     // concat channels
constexpr int CO    = 32;
constexpr int C2    = 70;
constexpr int NT    = 16;     // n per block
constexpr int POS   = 256;    // positions (n,k) per block
constexpr int XT    = 260;    // col-major position stride in dwords (256 + 4 pad)
                              // bank(col,pos) = (4*col + pos) % 32:
                              //   b128 imgf writes: lanes q -> 4q+4col -> all 32 banks, optimal
                              //   A-frag b32 reads: 16*quad + m16 -> 2-way (free)
constexpr int PPAD  = 76;
constexpr int NK    = N_ * K_;
constexpr int NCP   = C_IMG / 2;          // 27 channel-pairs
constexpr int ITEMS = NCP * (POS / 4);    // 27 * 64 = 1728 staging items
constexpr int ITERS = (ITEMS + 255) / 256; // 7 (last iter: t < 192)

__device__ inline u32 pkbf(float a, float b) {      // pack 2 fp32 -> 2 bf16 (RNE), a in low half
    union { __hip_bfloat162 h; u32 u; } cv;
    cv.h = __float22bfloat162_rn(make_float2(a, b));
    return cv.u;
}

// Block = (b, 16-n tile) = 256 positions. Phase A: build bf16 concat X in LDS,
// stored COLUMN-major x_lds[col][pos] so imgf stages as dwordx4 loads over k
// + conflict-free ds_write_b128 (4 positions x 1 col per thread-iteration).
// Phase M: 4 waves x 16 mfma_f32_16x16x32_bf16 -> h, BN1+ReLU in D-frag,
// pool over k via reg-reduce + shfl_xor(16,32) -> pooled LDS.
// Phase C: conv2+bn2+relu (fp32 VALU, cheap) -> out.
__global__ __launch_bounds__(256, 4) void pif_mfma_kernel(
    const float* __restrict__ points, const float* __restrict__ imgf,
    const float* __restrict__ dist,   const int*   __restrict__ idx,
    const float* __restrict__ w1, const float* __restrict__ b1,
    const float* __restrict__ g1, const float* __restrict__ be1,
    const float* __restrict__ m1, const float* __restrict__ v1,
    const float* __restrict__ w2, const float* __restrict__ b2,
    const float* __restrict__ g2, const float* __restrict__ be2,
    const float* __restrict__ m2, const float* __restrict__ v2,
    float* __restrict__ out)
{
    __shared__ u32   x_lds[32 * XT];        // 33280 B, x_lds[col][pos]
    __shared__ float pooled[NT][PPAD];      //  4864 B (total 38144 -> 4 blocks/CU)

    const int t   = threadIdx.x;
    const int tpb = N_ / NT;
    const int b   = blockIdx.x / tpb;
    const int n0  = (blockIdx.x % tpb) * NT;

    // ---------------- Phase A1: issue all imgf loads (x4 over positions) ----------------
    // item = (channel-pair cp, position-quad q); cp = item>>6 is wave-uniform,
    // q = item&63 = lane -> loads are 1 KiB/wave fully-coalesced dwordx4.
    const float* ib = imgf + (size_t)b * C_IMG * NK + n0 * K_;
    float4 va[ITERS], vb[ITERS];
    #pragma unroll
    for (int jj = 0; jj < ITERS; ++jj) {
        if (jj < ITERS - 1 || t < ITEMS - (ITERS - 1) * 256) {
            const int item = t + jj * 256;
            const int cp = item >> 6, q = item & 63;
            const float* p0 = ib + (size_t)(2 * cp) * NK + 4 * q;
            va[jj] = *(const float4*)p0;
            vb[jj] = *(const float4*)(p0 + NK);
        }
    }

    // ---------------- Phase A2: computed channels (cols 0..4), per-position ----------------
    const int k = t & 15, ln = t >> 4, n = n0 + ln;
    const int   base_nk = (b * N_ + n) * K_ + k;
    const int   j  = idx[base_nk];
    const float dv = dist[base_nk];
    const int   pb = (b * N_ + n) * 3;
    const float px = points[pb], py = points[pb + 1], pz = points[pb + 2];
    const int   qb = (b * N_ + j) * 3;
    const float qx = points[qb], qy = points[qb + 1], qz = points[qb + 2];

    x_lds[0 * XT + t] = pkbf(px, py);
    x_lds[1 * XT + t] = pkbf(pz, qx);
    x_lds[2 * XT + t] = pkbf(qy, qz);
    x_lds[3 * XT + t] = pkbf(px - qx, py - qy);
    x_lds[4 * XT + t] = pkbf(pz - qz, dv);

    // ---------------- Phase A3: pack + write imgf (conflict-free b128) ----------------
    #pragma unroll
    for (int jj = 0; jj < ITERS; ++jj) {
        if (jj < ITERS - 1 || t < ITEMS - (ITERS - 1) * 256) {
            const int item = t + jj * 256;
            const int cp = item >> 6, q = item & 63;
            uint4 pk;
            pk.x = pkbf(va[jj].x, vb[jj].x);
            pk.y = pkbf(va[jj].y, vb[jj].y);
            pk.z = pkbf(va[jj].z, vb[jj].z);
            pk.w = pkbf(va[jj].w, vb[jj].w);
            *(uint4*)&x_lds[(5 + cp) * XT + 4 * q] = pk;
        }
    }

    const int w = t >> 6, lane = t & 63, m16 = lane & 15, quad = lane >> 4;

    // B-frags: B[k=c][n=o], lane n=m16 reads w1[o][c..c+7] (row-major, contiguous)
    short8 bfrag[2][2];
    float  inv1v[2], add1v[2];
    #pragma unroll
    for (int ot = 0; ot < 2; ++ot) {
        const int o = ot * 16 + m16;
        #pragma unroll
        for (int kc = 0; kc < 2; ++kc) {
            const float* wr = w1 + o * C1 + kc * 32 + quad * 8;
            union { u32 u[4]; short8 v; } bf;
            bf.u[0] = pkbf(wr[0], wr[1]); bf.u[1] = pkbf(wr[2], wr[3]);
            bf.u[2] = pkbf(wr[4], wr[5]); bf.u[3] = pkbf(wr[6], wr[7]);
            bfrag[ot][kc] = bf.v;
        }
        const float iv = g1[o] * rsqrtf(v1[o] + BN_EPS);
        inv1v[ot] = iv;
        add1v[ot] = be1[o] - m1[o] * iv + b1[o] * iv;
    }

    // ep channels of pooled (max == mean == value)
    if (t < 48) {
        const int nn = t & 15, jj = t >> 4;
        const float v = points[(b * N_ + n0 + nn) * 3 + jj];
        pooled[nn][32 + jj] = v;
        pooled[nn][67 + jj] = v;
    }

    __syncthreads();

    // ---------------- Phase M: MFMA conv1 ----------------
    f32x4 acc[4][2];
    #pragma unroll
    for (int mt = 0; mt < 4; ++mt)
        #pragma unroll
        for (int ot = 0; ot < 2; ++ot)
            acc[mt][ot] = (f32x4){0.f, 0.f, 0.f, 0.f};

    #pragma unroll
    for (int mt = 0; mt < 4; ++mt) {
        const int prow = w * 64 + mt * 16 + m16;
        #pragma unroll
        for (int kc = 0; kc < 2; ++kc) {
            // A[m=lane&15][c = kc*32 + quad*8 + j]: 4 strided b32 reads (2-way, free)
            const u32* cb = &x_lds[(kc * 16 + quad * 4) * XT + prow];
            union { u32 u[4]; short8 v; } af;
            af.u[0] = cb[0];
            af.u[1] = cb[XT];
            af.u[2] = cb[2 * XT];
            af.u[3] = cb[3 * XT];
            acc[mt][0] = __builtin_amdgcn_mfma_f32_16x16x32_bf16(af.v, bfrag[0][kc], acc[mt][0], 0, 0, 0);
            acc[mt][1] = __builtin_amdgcn_mfma_f32_16x16x32_bf16(af.v, bfrag[1][kc], acc[mt][1], 0, 0, 0);
        }
    }

    // BN1 + ReLU + pool over k (k = quad*4 + reg within mtile)
    #pragma unroll
    for (int mt = 0; mt < 4; ++mt) {
        #pragma unroll
        for (int ot = 0; ot < 2; ++ot) {
            float mx = 0.f, sm = 0.f;
            #pragma unroll
            for (int r = 0; r < 4; ++r) {
                float hv = fmaf(acc[mt][ot][r], inv1v[ot], add1v[ot]);
                hv = fmaxf(hv, 0.f);
                mx = fmaxf(mx, hv);
                sm += hv;
            }
            mx = fmaxf(mx, __shfl_xor(mx, 16));
            mx = fmaxf(mx, __shfl_xor(mx, 32));
            sm += __shfl_xor(sm, 16);
            sm += __shfl_xor(sm, 32);
            if (quad == 0) {
                const int nn = w * 4 + mt;
                pooled[nn][ot * 16 + m16]      = mx;
                pooled[nn][35 + ot * 16 + m16] = sm * (1.f / 16.f);
            }
        }
    }
    __syncthreads();

    // ---------------- Phase C: conv2 + bn2 + relu (fp32) ----------------
    #pragma unroll
    for (int r = 0; r < 2; ++r) {
        const int nn = t & 15;
        const int o  = (t >> 4) + r * 16;
        const float* wr = w2 + o * C2;
        float a0 = 0.f, a1 = 0.f;
        #pragma unroll
        for (int c = 0; c < C2; c += 2) {
            a0 = fmaf(wr[c],     pooled[nn][c],     a0);
            a1 = fmaf(wr[c + 1], pooled[nn][c + 1], a1);
        }
        const float acc2 = a0 + a1;
        const float iv = g2[o] * rsqrtf(v2[o] + BN_EPS);
        float ov = fmaf(acc2 + b2[o], iv, be2[o] - m2[o] * iv);
        ov = fmaxf(ov, 0.f);
        out[(b * CO + o) * N_ + n0 + nn] = ov;
    }
}

extern "C" void kernel_launch(void* const* d_in, const int* in_sizes, int n_in,
                              void* d_out, int out_size, void* d_ws, size_t ws_size,
                              hipStream_t stream) {
    const float* points = (const float*)d_in[0];
    const float* imgf   = (const float*)d_in[1];
    const float* dist   = (const float*)d_in[2];
    const int*   idx    = (const int*)  d_in[3];
    const float* w1     = (const float*)d_in[4];
    const float* b1     = (const float*)d_in[5];
    const float* g1     = (const float*)d_in[6];
    const float* be1    = (const float*)d_in[7];
    const float* m1     = (const float*)d_in[8];
    const float* v1     = (const float*)d_in[9];
    const float* w2     = (const float*)d_in[10];
    const float* b2     = (const float*)d_in[11];
    const float* g2     = (const float*)d_in[12];
    const float* be2    = (const float*)d_in[13];
    const float* m2     = (const float*)d_in[14];
    const float* v2     = (const float*)d_in[15];
    float* out          = (float*)d_out;

    const int blocks = B_ * (N_ / NT);       // 4096
    pif_mfma_kernel<<<blocks, 256, 0, stream>>>(
        points, imgf, dist, idx,
        w1, b1, g1, be1, m1, v1,
        w2, b2, g2, be2, m2, v2, out);
}

// Round 2
// 355.962 us; speedup vs baseline: 1.0092x; 1.0092x over previous
//
#include <hip/hip_runtime.h>
#include <hip/hip_bf16.h>
#include <cmath>

#define BN_EPS 1e-6f
typedef unsigned int u32;
typedef __attribute__((ext_vector_type(8))) short short8;   // 8 bf16 (4 VGPRs)
typedef __attribute__((ext_vector_type(4))) float f32x4;    // MFMA accum

constexpr int B_    = 4;
constexpr int N_    = 16384;
constexpr int K_    = 16;
constexpr int C_IMG = 54;
constexpr int C1    = 64;     // concat channels
constexpr int CO    = 32;
constexpr int C2    = 70;
constexpr int NT    = 16;     // n per block
constexpr int POS   = 256;    // positions (n,k) per block
constexpr int XT    = 256;    // fp32 X row stride (positions); row = one channel
constexpr int PPAD  = 76;
constexpr int NK    = N_ * K_;

__device__ inline u32 pkbf(float a, float b) {      // pack 2 fp32 -> 2 bf16 (RNE), a in low half
    union { __hip_bfloat162 h; u32 u; } cv;
    cv.h = __float22bfloat162_rn(make_float2(a, b));
    return cv.u;
}

// Block = (b, 16-n tile) = 256 positions.
// Phase A: X tile kept fp32 in LDS, layout x[channel][pos].
//   - channels 10..63 (imgf): global_load_lds width=16, one DMA instr per channel
//     (wave-uniform LDS row base + lane*16B; per-lane contiguous global src).
//     No VGPR round-trip -> full 54KB/block in flight, HBM latency hidden by queue.
//   - channels 0..9 (ep,nb,ep-nb,dist): per-thread fp32 scalar stores.
// Phase M: A-frag = 8 ds_read_b32 (stride XT rows) + 4 pkbf packs -> mfma bf16.
//   BN1+ReLU in D-frag, pool over k via reg-reduce + shfl_xor(16,32) -> pooled LDS.
// Phase C: conv2+bn2+relu (fp32 VALU, cheap) -> out.
__global__ __launch_bounds__(256, 2) void pif_mfma_kernel(
    const float* __restrict__ points, const float* __restrict__ imgf,
    const float* __restrict__ dist,   const int*   __restrict__ idx,
    const float* __restrict__ w1, const float* __restrict__ b1,
    const float* __restrict__ g1, const float* __restrict__ be1,
    const float* __restrict__ m1, const float* __restrict__ v1,
    const float* __restrict__ w2, const float* __restrict__ b2,
    const float* __restrict__ g2, const float* __restrict__ be2,
    const float* __restrict__ m2, const float* __restrict__ v2,
    float* __restrict__ out)
{
    __shared__ float xf[64 * XT];           // 65536 B, xf[ch*XT + pos]
    __shared__ float pooled[NT][PPAD];      //  4864 B (total 70400 -> 2 blocks/CU)

    const int t    = threadIdx.x;
    const int tpb  = N_ / NT;
    const int b    = blockIdx.x / tpb;
    const int n0   = (blockIdx.x % tpb) * NT;
    const int lane = t & 63;
    const int w    = t >> 6;

    // ---------------- Phase A0: issue idx/dist early (long dependent chain) ----------
    const int k = t & 15, ln = t >> 4, n = n0 + ln;
    const int   base_nk = (b * N_ + n) * K_ + k;
    const int   j  = idx[base_nk];
    const float dv = dist[base_nk];

    // ---------------- Phase A1: imgf -> LDS via DMA (rows 10..63) --------------------
    // wave w stages channels c = w, w+4, ... ; each instr: 64 lanes x 16B = 1KB row.
    const float* ib = imgf + (size_t)b * C_IMG * NK + n0 * K_;
    #pragma unroll
    for (int i = 0; i < 14; ++i) {
        const int c = w + 4 * i;
        if (c < C_IMG) {
            const float* gsrc = ib + (size_t)c * NK + (lane << 2);
            float* ldst = &xf[(10 + c) * XT];
            __builtin_amdgcn_global_load_lds(
                (const __attribute__((address_space(1))) void*)gsrc,
                (__attribute__((address_space(3))) void*)ldst, 16, 0, 0);
        }
    }

    // ---------------- Phase A2: computed channels (rows 0..9), per-position ----------
    const int   pb = (b * N_ + n) * 3;
    const float px = points[pb], py = points[pb + 1], pz = points[pb + 2];
    const int   qb = (b * N_ + j) * 3;
    const float qx = points[qb], qy = points[qb + 1], qz = points[qb + 2];

    xf[0 * XT + t] = px;
    xf[1 * XT + t] = py;
    xf[2 * XT + t] = pz;
    xf[3 * XT + t] = qx;
    xf[4 * XT + t] = qy;
    xf[5 * XT + t] = qz;
    xf[6 * XT + t] = px - qx;
    xf[7 * XT + t] = py - qy;
    xf[8 * XT + t] = pz - qz;
    xf[9 * XT + t] = dv;

    const int m16 = lane & 15, quad = lane >> 4;

    // B-frags: B[k=c][n=o], lane n=m16 reads w1[o][c..c+7] (row-major, contiguous)
    short8 bfrag[2][2];
    float  inv1v[2], add1v[2];
    #pragma unroll
    for (int ot = 0; ot < 2; ++ot) {
        const int o = ot * 16 + m16;
        #pragma unroll
        for (int kc = 0; kc < 2; ++kc) {
            const float* wr = w1 + o * C1 + kc * 32 + quad * 8;
            union { u32 u[4]; short8 v; } bf;
            bf.u[0] = pkbf(wr[0], wr[1]); bf.u[1] = pkbf(wr[2], wr[3]);
            bf.u[2] = pkbf(wr[4], wr[5]); bf.u[3] = pkbf(wr[6], wr[7]);
            bfrag[ot][kc] = bf.v;
        }
        const float iv = g1[o] * rsqrtf(v1[o] + BN_EPS);
        inv1v[ot] = iv;
        add1v[ot] = be1[o] - m1[o] * iv + b1[o] * iv;
    }

    // ep channels of pooled (max == mean == value)
    if (t < 48) {
        const int nn = t & 15, jj = t >> 4;
        const float v = points[(b * N_ + n0 + nn) * 3 + jj];
        pooled[nn][32 + jj] = v;
        pooled[nn][67 + jj] = v;
    }

    __syncthreads();   // drains vmcnt (DMA) + lgkmcnt

    // ---------------- Phase M: MFMA conv1 ----------------
    f32x4 acc[4][2];
    #pragma unroll
    for (int mt = 0; mt < 4; ++mt)
        #pragma unroll
        for (int ot = 0; ot < 2; ++ot)
            acc[mt][ot] = (f32x4){0.f, 0.f, 0.f, 0.f};

    #pragma unroll
    for (int mt = 0; mt < 4; ++mt) {
        const int prow = w * 64 + mt * 16 + m16;
        #pragma unroll
        for (int kc = 0; kc < 2; ++kc) {
            // A[m=prow][c = kc*32 + quad*8 + j]: 8 strided b32 reads + 4 packs
            const float* cb = &xf[(kc * 32 + quad * 8) * XT + prow];
            float v0 = cb[0 * XT], v1_ = cb[1 * XT], v2_ = cb[2 * XT], v3 = cb[3 * XT];
            float v4 = cb[4 * XT], v5 = cb[5 * XT], v6 = cb[6 * XT], v7 = cb[7 * XT];
            union { u32 u[4]; short8 v; } af;
            af.u[0] = pkbf(v0, v1_);
            af.u[1] = pkbf(v2_, v3);
            af.u[2] = pkbf(v4, v5);
            af.u[3] = pkbf(v6, v7);
            acc[mt][0] = __builtin_amdgcn_mfma_f32_16x16x32_bf16(af.v, bfrag[0][kc], acc[mt][0], 0, 0, 0);
            acc[mt][1] = __builtin_amdgcn_mfma_f32_16x16x32_bf16(af.v, bfrag[1][kc], acc[mt][1], 0, 0, 0);
        }
    }

    // BN1 + ReLU + pool over k (k = quad*4 + reg within mtile)
    #pragma unroll
    for (int mt = 0; mt < 4; ++mt) {
        #pragma unroll
        for (int ot = 0; ot < 2; ++ot) {
            float mx = 0.f, sm = 0.f;
            #pragma unroll
            for (int r = 0; r < 4; ++r) {
                float hv = fmaf(acc[mt][ot][r], inv1v[ot], add1v[ot]);
                hv = fmaxf(hv, 0.f);
                mx = fmaxf(mx, hv);
                sm += hv;
            }
            mx = fmaxf(mx, __shfl_xor(mx, 16));
            mx = fmaxf(mx, __shfl_xor(mx, 32));
            sm += __shfl_xor(sm, 16);
            sm += __shfl_xor(sm, 32);
            if (quad == 0) {
                const int nn = w * 4 + mt;
                pooled[nn][ot * 16 + m16]      = mx;
                pooled[nn][35 + ot * 16 + m16] = sm * (1.f / 16.f);
            }
        }
    }
    __syncthreads();

    // ---------------- Phase C: conv2 + bn2 + relu (fp32) ----------------
    #pragma unroll
    for (int r = 0; r < 2; ++r) {
        const int nn = t & 15;
        const int o  = (t >> 4) + r * 16;
        const float* wr = w2 + o * C2;
        float a0 = 0.f, a1 = 0.f;
        #pragma unroll
        for (int c = 0; c < C2; c += 2) {
            a0 = fmaf(wr[c],     pooled[nn][c],     a0);
            a1 = fmaf(wr[c + 1], pooled[nn][c + 1], a1);
        }
        const float acc2 = a0 + a1;
        const float iv = g2[o] * rsqrtf(v2[o] + BN_EPS);
        float ov = fmaf(acc2 + b2[o], iv, be2[o] - m2[o] * iv);
        ov = fmaxf(ov, 0.f);
        out[(b * CO + o) * N_ + n0 + nn] = ov;
    }
}

extern "C" void kernel_launch(void* const* d_in, const int* in_sizes, int n_in,
                              void* d_out, int out_size, void* d_ws, size_t ws_size,
                              hipStream_t stream) {
    const float* points = (const float*)d_in[0];
    const float* imgf   = (const float*)d_in[1];
    const float* dist   = (const float*)d_in[2];
    const int*   idx    = (const int*)  d_in[3];
    const float* w1     = (const float*)d_in[4];
    const float* b1     = (const float*)d_in[5];
    const float* g1     = (const float*)d_in[6];
    const float* be1    = (const float*)d_in[7];
    const float* m1     = (const float*)d_in[8];
    const float* v1     = (const float*)d_in[9];
    const float* w2     = (const float*)d_in[10];
    const float* b2     = (const float*)d_in[11];
    const float* g2     = (const float*)d_in[12];
    const float* be2    = (const float*)d_in[13];
    const float* m2     = (const float*)d_in[14];
    const float* v2     = (const float*)d_in[15];
    float* out          = (float*)d_out;

    const int blocks = B_ * (N_ / NT);       // 4096
    pif_mfma_kernel<<<blocks, 256, 0, stream>>>(
        points, imgf, dist, idx,
        w1, b1, g1, be1, m1, v1,
        w2, b2, g2, be2, m2, v2, out);
}